// Round 6
// baseline (654.564 us; speedup 1.0000x reference)
//
#include <hip/hip_runtime.h>
#include <hip/hip_bf16.h>

// Problem constants
#define BATCH 32
#define NSEQ  16384
#define DDIM  65
#define CHUNK 64
#define KQ    64
#define NBLK  256          // NSEQ / CHUNK
#define SCALE 0.12403473458920847f   // 65^-0.5
#define TCH   4            // chunks per block (k_attn)
#define GRP   64           // NBLK / TCH

typedef __bf16 bf16x8 __attribute__((ext_vector_type(8)));
typedef float  f32x4  __attribute__((ext_vector_type(4)));
#define MFMA16(a, b, c) __builtin_amdgcn_mfma_f32_16x16x32_bf16(a, b, c, 0, 0, 0)

__device__ __forceinline__ float gelu_exact(float v) {
    return 0.5f * v * (1.0f + erff(v * 0.7071067811865476f));
}

// tanh-approx GELU in sigmoid form (validated rounds 3-5, same absmax):
// gelu = x * sigmoid(1.5957691x(1+0.044715x^2)); |err| <= ~2e-4.
__device__ __forceinline__ float gelu_tanh(float x) {
    float x2 = x * x;
    float z  = x * fmaf(-0.07135481627f, x2, -1.59576912161f);  // -2t
    float e  = __expf(z);
    return x * __builtin_amdgcn_rcpf(e + 1.0f);
}

// ---------------------------------------------------------------------------
// Kernel 0: transpose+pad Wk,Wv to bf16 WT[80][64]: WT[d][e] = W[e][d], rows
// 65..79 zero.  (round-0 version, proven)
// ---------------------------------------------------------------------------
__global__ __launch_bounds__(256) void k_prep(const float* __restrict__ Wk,
                                              const float* __restrict__ Wv,
                                              __bf16* __restrict__ WkT,
                                              __bf16* __restrict__ WvT) {
    int i = blockIdx.x * 256 + threadIdx.x;     // 0 .. 2*80*64-1
    if (i >= 2 * 80 * 64) return;
    int m = i / 5120;
    int j = i - m * 5120;
    int d = j >> 6, e = j & 63;
    const float* W = m ? Wv : Wk;
    __bf16* T = m ? WvT : WkT;
    T[(size_t)d * 64 + e] = (d < DDIM) ? (__bf16)W[e * DDIM + d] : (__bf16)0.0f;
}

// ---------------------------------------------------------------------------
// Kernel 1: per-slice partial sums over N (no atomics).  grid (64, 32).
// ---------------------------------------------------------------------------
__global__ __launch_bounds__(256) void k_gavg(const float* __restrict__ x,
                                              float* __restrict__ partial) {
    const int s = blockIdx.x;
    const int b = blockIdx.y;
    const int tid = threadIdx.x;
    const int w = tid >> 6, lane = tid & 63;
    const float* xb = x + (size_t)b * NSEQ * DDIM;
    const int n0 = s * 256;
    float acc = 0.f, acce = 0.f;
    #pragma unroll 4
    for (int i = 0; i < 64; ++i) {
        const float* row = xb + (size_t)(n0 + w + i * 4) * DDIM;
        acc  += row[lane];
        acce += row[64];
    }
    __shared__ float part[4][DDIM];
    part[w][lane] = acc;
    if (lane == 0) part[w][64] = acce;
    __syncthreads();
    if (tid < DDIM) {
        partial[((size_t)b * 64 + s) * DDIM + tid] =
            part[0][tid] + part[1][tid] + part[2][tid] + part[3][tid];
    }
}

// ---------------------------------------------------------------------------
// Kernel 2a: reduce partials -> gavg; h = gelu(gavg@Wq1+bq1); r = gavg@Wr+br.
// ---------------------------------------------------------------------------
__global__ __launch_bounds__(256) void k_qgen1(const float* __restrict__ partial,
    const float* __restrict__ Wq1, const float* __restrict__ bq1,
    const float* __restrict__ Wr,  const float* __restrict__ br,
    float* __restrict__ h_out, float* __restrict__ r_out) {
    const int b = blockIdx.x, tid = threadIdx.x;
    __shared__ float g[DDIM];
    if (tid < DDIM) {
        float a = 0.f;
        const float* p = partial + (size_t)b * 64 * DDIM + tid;
        #pragma unroll 8
        for (int s = 0; s < 64; ++s) a += p[s * DDIM];
        g[tid] = a * (1.0f / 16384.0f);
    }
    __syncthreads();
    if (tid < DDIM) {
        float a = bq1[tid];
        for (int e = 0; e < DDIM; ++e) a += g[e] * Wq1[e * DDIM + tid];
        h_out[b * DDIM + tid] = gelu_exact(a);
    } else if (tid >= 128 && tid < 128 + DDIM) {
        const int d = tid - 128;
        float a = br[d];
        for (int e = 0; e < DDIM; ++e) a += g[e] * Wr[e * DDIM + d];
        r_out[b * DDIM + d] = a;
    }
}

// ---------------------------------------------------------------------------
// Kernel 2b: q = (h@Wq2+bq2)*SCALE -> qbf [64][64] bf16 + q64 col.
// ---------------------------------------------------------------------------
__global__ __launch_bounds__(256) void k_qgen2(const float* __restrict__ h_in,
    const float* __restrict__ Wq2, const float* __restrict__ bq2,
    __bf16* __restrict__ qbf, float* __restrict__ q64) {
    const int b = blockIdx.y, tid = threadIdx.x;
    const int o = blockIdx.x * 256 + tid;
    __shared__ float h[DDIM];
    if (tid < DDIM) h[tid] = h_in[b * DDIM + tid];
    __syncthreads();
    if (o >= KQ * DDIM) return;
    float a = bq2[o];
    #pragma unroll 13
    for (int e = 0; e < DDIM; ++e) a += h[e] * Wq2[e * (KQ * DDIM) + o];
    a *= SCALE;
    const int k = o / DDIM, d = o - k * DDIM;
    if (d < 64) qbf[(size_t)b * 4096 + k * 64 + d] = (__bf16)a;
    else        q64[b * 64 + k] = a;
}

// ---------------------------------------------------------------------------
// Kernel 3 (MFMA): grid (GRP=64, BATCH).  Round-0 attn body (proven 145 us,
// 48 VGPR, no spill) wrapped in a TCH=4 loop:
//  * x double-buffered in LDS (xPbuf[2]); P reuses the current x buffer.
//  * T14 stage split: next chunk's 16 f32 loads issue right after the mid
//    barrier (hide under ph3/ph5 MFMAs); ds-writes land after ph5.
//  * q fragments hoisted (amortized over 4 chunks).  2 barriers/chunk.
//  * NO online softmax, NO persistent O-state: blk/cs written per chunk
//    exactly like round 0 (k_cross unchanged).
// LDS 37.6 KB -> 4 blocks/CU.
// ---------------------------------------------------------------------------
__global__ __launch_bounds__(256, 4) void k_attn(const float* __restrict__ x,
    const __bf16* __restrict__ qbf, const float* __restrict__ q64g,
    const __bf16* __restrict__ WkT, const __bf16* __restrict__ WvT,
    const float* __restrict__ Wk, const float* __restrict__ bkb,
    const float* __restrict__ Wv, const float* __restrict__ bvb,
    const float* __restrict__ pos, const float* __restrict__ cq,
    __bf16* __restrict__ blk_out, float* __restrict__ cs_out) {
    const int g   = blockIdx.x;
    const int b   = blockIdx.y;
    const int nb0 = g * TCH;
    const int tid = threadIdx.x;
    const int lane = tid & 63, w = tid >> 6;
    const int l16 = lane & 15, quad = lane >> 4;

    __shared__ __align__(16) __bf16 xPbuf[2][64 * 72]; // x chunk then P, A/B
    __shared__ __align__(16) __bf16 keys[64 * 72];     // [c][d], cols 0..64
    __shared__ __align__(16) __bf16 valsT[64 * 72];    // [d][c], d<64
    __shared__ float vals64[64];                       // vals[c][64] fp32
    __shared__ float xs64[2][64];                      // x[c][64], A/B

    // hoisted q fragments (loop-invariant; loads overlap prologue stage)
    const __bf16* aq = qbf + (size_t)b * 4096 + (w * 16 + l16) * 64 + quad * 8;
    const bf16x8 qa0 = *(const bf16x8*)aq;
    const bf16x8 qa1 = *(const bf16x8*)(aq + 32);
    const f32x4 q64v = *(const f32x4*)(q64g + b * 64 + w * 16 + quad * 4);
    const float cq64 = cq[64];

    // staging mapping (round-0): 4 threads per row, own-wave rows.
    const int cst = tid >> 2, gst = tid & 3;

    // ---- prologue: stage chunk 0 into buffer 0 ----
    {
        const float* xrow =
            x + ((size_t)b * NSEQ + (size_t)nb0 * CHUNK + cst) * DDIM;
        __bf16* dst = xPbuf[0] + cst * 72;
        #pragma unroll
        for (int j = 0; j < 16; ++j)
            dst[gst + 4 * j] = (__bf16)xrow[gst + 4 * j];
        if (gst == 0) xs64[0][cst] = xrow[64];
    }
    __syncthreads();

    for (int t = 0; t < TCH; ++t) {
        const int cur = t & 1;
        const int nb  = nb0 + t;
        __bf16* xP = xPbuf[cur];

        // ---- ph2: keys/vals via MFMA (round-0 body) ----
        {
            const __bf16* arow = xP + (w * 16 + l16) * 72 + quad * 8;
            bf16x8 a0 = *(const bf16x8*)arow;
            bf16x8 a1 = *(const bf16x8*)(arow + 32);
            f32x4 ak[5], av[5];
            const f32x4 z = {0.f, 0.f, 0.f, 0.f};
            #pragma unroll
            for (int nt = 0; nt < 5; ++nt) {
                const __bf16* bkr = WkT + (nt * 16 + l16) * 64 + quad * 8;
                const __bf16* bvr = WvT + (nt * 16 + l16) * 64 + quad * 8;
                ak[nt] = MFMA16(a0, *(const bf16x8*)bkr, z);
                ak[nt] = MFMA16(a1, *(const bf16x8*)(bkr + 32), ak[nt]);
                av[nt] = MFMA16(a0, *(const bf16x8*)bvr, z);
                av[nt] = MFMA16(a1, *(const bf16x8*)(bvr + 32), av[nt]);
            }
            float xe[4];
            #pragma unroll
            for (int r = 0; r < 4; ++r) xe[r] = xs64[cur][w * 16 + quad * 4 + r];
            #pragma unroll
            for (int nt = 0; nt < 5; ++nt) {
                const int d = nt * 16 + l16;
                if (d <= 64) {
                    const float wk64d = Wk[64 * DDIM + d];
                    const float wv64d = Wv[64 * DDIM + d];
                    const float bkd = bkb[d], bvd = bvb[d];
                    #pragma unroll
                    for (int r = 0; r < 4; ++r) {
                        const int c = w * 16 + quad * 4 + r;
                        const float pv = pos[c * DDIM + d];
                        const float kvv = gelu_tanh(ak[nt][r] + xe[r] * wk64d + bkd) + pv;
                        const float vvv = gelu_tanh(av[nt][r] + xe[r] * wv64d + bvd) + pv;
                        keys[c * 72 + d] = (__bf16)kvv;
                        if (d < 64) valsT[d * 72 + c] = (__bf16)vvv;
                        else        vals64[c] = vvv;
                    }
                }
            }
        }
        __syncthreads();   // mid barrier: keys/valsT/vals64 published

        // ---- T14 issue-early: next chunk's x loads into registers ----
        float xr[16], xen;
        if (t + 1 < TCH) {
            const float* xrow =
                x + ((size_t)b * NSEQ + (size_t)(nb + 1) * CHUNK + cst) * DDIM;
            #pragma unroll
            for (int j = 0; j < 16; ++j) xr[j] = xrow[gst + 4 * j];
            xen = (gst == 0) ? xrow[64] : 0.f;
        }

        // ---- ph3: S = q@keys^T + fixup, softmax, P store, d=64 column ----
        float csr[4];
        {
            const f32x4 z = {0.f, 0.f, 0.f, 0.f};
            float st[4][4];                 // [nt][r]
            #pragma unroll
            for (int nt = 0; nt < 4; ++nt) {
                const __bf16* kb = keys + (nt * 16 + l16) * 72 + quad * 8;
                f32x4 sacc = MFMA16(qa0, *(const bf16x8*)kb, z);
                sacc = MFMA16(qa1, *(const bf16x8*)(kb + 32), sacc);
                const float k64c = (float)keys[(nt * 16 + l16) * 72 + 64];
                #pragma unroll
                for (int r = 0; r < 4; ++r)
                    st[nt][r] = fmaf(q64v[r], k64c, sacc[r]) * SCALE;
            }
            float mr[4], sum[4], inv[4];
            #pragma unroll
            for (int r = 0; r < 4; ++r) {
                float m = fmaxf(fmaxf(st[0][r], st[1][r]), fmaxf(st[2][r], st[3][r]));
                m = fmaxf(m, __shfl_xor(m, 1));
                m = fmaxf(m, __shfl_xor(m, 2));
                m = fmaxf(m, __shfl_xor(m, 4));
                m = fmaxf(m, __shfl_xor(m, 8));
                mr[r] = m;
                sum[r] = 0.f;
            }
            #pragma unroll
            for (int nt = 0; nt < 4; ++nt)
                #pragma unroll
                for (int r = 0; r < 4; ++r) {
                    st[nt][r] = __expf(st[nt][r] - mr[r]);
                    sum[r] += st[nt][r];
                }
            #pragma unroll
            for (int r = 0; r < 4; ++r) {
                float s = sum[r];
                s += __shfl_xor(s, 1);
                s += __shfl_xor(s, 2);
                s += __shfl_xor(s, 4);
                s += __shfl_xor(s, 8);
                inv[r] = __builtin_amdgcn_rcpf(s);
            }
            // store normalized P (bf16) into current x buffer (x dead)
            #pragma unroll
            for (int nt = 0; nt < 4; ++nt)
                #pragma unroll
                for (int r = 0; r < 4; ++r)
                    xP[(w * 16 + quad * 4 + r) * 72 + nt * 16 + l16] =
                        (__bf16)(st[nt][r] * inv[r]);
            // d=64 output column from fp32 P
            float v64l[4];
            #pragma unroll
            for (int nt = 0; nt < 4; ++nt) v64l[nt] = vals64[nt * 16 + l16];
            #pragma unroll
            for (int r = 0; r < 4; ++r) {
                float o = st[0][r] * v64l[0];
                o = fmaf(st[1][r], v64l[1], o);
                o = fmaf(st[2][r], v64l[2], o);
                o = fmaf(st[3][r], v64l[3], o);
                o += __shfl_xor(o, 1);
                o += __shfl_xor(o, 2);
                o += __shfl_xor(o, 4);
                o += __shfl_xor(o, 8);
                csr[r] = 0.f;
                if (l16 == 0) {
                    const float o64 = o * inv[r];
                    const int k = w * 16 + quad * 4 + r;
                    blk_out[(((size_t)b * KQ + k) * NBLK + nb) * DDIM + 64] =
                        (__bf16)o64;
                    csr[r] = o64 * cq64;
                }
            }
        }
        // NO barrier: each wave reads back only the P rows it wrote.

        // ---- ph5: blk = P @ vals (round-0 body) + cs ----
        {
            const __bf16* pr = xP + (w * 16 + l16) * 72 + quad * 8;
            bf16x8 pa0 = *(const bf16x8*)pr;
            bf16x8 pa1 = *(const bf16x8*)(pr + 32);
            const f32x4 z = {0.f, 0.f, 0.f, 0.f};
            #pragma unroll
            for (int nt = 0; nt < 4; ++nt) {
                const __bf16* vb = valsT + (nt * 16 + l16) * 72 + quad * 8;
                f32x4 o = MFMA16(pa0, *(const bf16x8*)vb, z);
                o = MFMA16(pa1, *(const bf16x8*)(vb + 32), o);
                const int d = nt * 16 + l16;
                const float cqd = cq[d];
                #pragma unroll
                for (int r = 0; r < 4; ++r) {
                    const int k = w * 16 + quad * 4 + r;
                    blk_out[(((size_t)b * KQ + k) * NBLK + nb) * DDIM + d] =
                        (__bf16)o[r];
                    csr[r] = fmaf(o[r], cqd, csr[r]);
                }
            }
            #pragma unroll
            for (int r = 0; r < 4; ++r) {
                float v = csr[r];
                v += __shfl_xor(v, 1);
                v += __shfl_xor(v, 2);
                v += __shfl_xor(v, 4);
                v += __shfl_xor(v, 8);
                if (l16 == 0) {
                    const int k = w * 16 + quad * 4 + r;
                    cs_out[((size_t)b * KQ + k) * NBLK + nb] = v * SCALE;
                }
            }
        }

        // ---- T14 write-late: stage next x into the other buffer ----
        if (t + 1 < TCH) {
            __bf16* dst = xPbuf[cur ^ 1] + cst * 72;
            #pragma unroll
            for (int j = 0; j < 16; ++j)
                dst[gst + 4 * j] = (__bf16)xr[j];
            if (gst == 0) xs64[cur ^ 1][cst] = xen;
        }
        __syncthreads();   // end barrier: keys/valsT free for next ph2
    }
}

// ---------------------------------------------------------------------------
// Kernel 4: cross softmax over nb, weighted sum of blk, residual, LayerNorm.
// (round-0 version, proven; blk layout [b][k][nb][65])
// ---------------------------------------------------------------------------
__global__ __launch_bounds__(256) void k_cross(
    const __bf16* __restrict__ blk, const float* __restrict__ cs,
    const float* __restrict__ r, const float* __restrict__ gamma,
    const float* __restrict__ beta, float* __restrict__ out) {
    const int bk_ = blockIdx.x;
    const int b = bk_ >> 6;
    const int tid = threadIdx.x;
    const int w = tid >> 6, lane = tid & 63;

    __shared__ float ew[NBLK];
    __shared__ float red[4][DDIM];
    __shared__ float vv[DDIM];
    __shared__ float wredA[4];
    __shared__ float stats[2];

    const float v = cs[(size_t)bk_ * NBLK + tid];
    float m = v;
    for (int off = 32; off; off >>= 1) m = fmaxf(m, __shfl_down(m, off));
    if (lane == 0) wredA[w] = m;
    __syncthreads();
    m = fmaxf(fmaxf(wredA[0], wredA[1]), fmaxf(wredA[2], wredA[3]));
    const float e = __expf(v - m);
    ew[tid] = e;
    float s = e;
    for (int off = 32; off; off >>= 1) s += __shfl_down(s, off);
    __syncthreads();
    if (lane == 0) wredA[w] = s;
    __syncthreads();
    const float inv = 1.0f / (wredA[0] + wredA[1] + wredA[2] + wredA[3]);

    const __bf16* base = blk + (size_t)bk_ * NBLK * DDIM;
    float acc = 0.f, acce = 0.f;
    #pragma unroll 4
    for (int i = 0; i < 64; ++i) {
        const int n = w + i * 4;
        const __bf16* row = base + n * DDIM;
        const float wgt = ew[n];
        acc  += wgt * (float)row[lane];
        acce += wgt * (float)row[64];
    }
    red[w][lane] = acc;
    if (lane == 0) red[w][64] = acce;
    __syncthreads();
    if (tid < DDIM) {
        vv[tid] = (red[0][tid] + red[1][tid] + red[2][tid] + red[3][tid]) * inv
                  + r[b * DDIM + tid];
    }
    __syncthreads();
    if (tid < 64) {
        float a  = vv[tid] + (tid == 0 ? vv[64] : 0.f);
        float sq = vv[tid] * vv[tid] + (tid == 0 ? vv[64] * vv[64] : 0.f);
        for (int off = 32; off; off >>= 1) {
            a  += __shfl_down(a, off);
            sq += __shfl_down(sq, off);
        }
        if (tid == 0) {
            const float mu  = a * (1.0f / DDIM);
            const float var = sq * (1.0f / DDIM) - mu * mu;
            stats[0] = mu;
            stats[1] = rsqrtf(var + 1e-5f);
        }
    }
    __syncthreads();
    if (tid < DDIM) {
        out[(size_t)bk_ * DDIM + tid] =
            (vv[tid] - stats[0]) * stats[1] * gamma[tid] + beta[tid];
    }
}

// ---------------------------------------------------------------------------
extern "C" void kernel_launch(void* const* d_in, const int* in_sizes, int n_in,
                              void* d_out, int out_size, void* d_ws, size_t ws_size,
                              hipStream_t stream) {
    const float* x    = (const float*)d_in[0];
    const float* Wq1  = (const float*)d_in[1];
    const float* bq1  = (const float*)d_in[2];
    const float* Wq2  = (const float*)d_in[3];
    const float* bq2  = (const float*)d_in[4];
    const float* Wk   = (const float*)d_in[5];
    const float* bk   = (const float*)d_in[6];
    const float* Wv   = (const float*)d_in[7];
    const float* bv   = (const float*)d_in[8];
    const float* cq   = (const float*)d_in[9];
    const float* pos  = (const float*)d_in[10];
    const float* Wr   = (const float*)d_in[11];
    const float* br   = (const float*)d_in[12];
    const float* gamma= (const float*)d_in[13];
    const float* beta = (const float*)d_in[14];
    float* out = (float*)d_out;

    // workspace layout (byte offsets, all 16B-aligned) -- round-0 layout
    char* w8 = (char*)d_ws;
    float*  partial = (float*)w8;                    // 532480 B @0
    float*  rres    = (float*)(w8 + 532480);         // 8320 B
    float*  q64     = (float*)(w8 + 540800);         // 8192 B
    float*  hbuf    = (float*)(w8 + 548992);         // 8320 B
    float*  cs      = (float*)(w8 + 557312);         // 2097152 B
    __bf16* qbf     = (__bf16*)(w8 + 2654464);       // 262144 B
    __bf16* WkT     = (__bf16*)(w8 + 2916608);       // 10240 B
    __bf16* WvT     = (__bf16*)(w8 + 2926848);       // 10240 B
    __bf16* blk     = (__bf16*)(w8 + 2937088);       // 68157440 B [b][k][nb][65]

    k_prep<<<40, 256, 0, stream>>>(Wk, Wv, WkT, WvT);
    k_gavg<<<dim3(64, BATCH), 256, 0, stream>>>(x, partial);
    k_qgen1<<<BATCH, 256, 0, stream>>>(partial, Wq1, bq1, Wr, br, hbuf, rres);
    k_qgen2<<<dim3(17, BATCH), 256, 0, stream>>>(hbuf, Wq2, bq2, qbf, q64);
    k_attn<<<dim3(GRP, BATCH), 256, 0, stream>>>(x, qbf, q64, WkT, WvT,
                                                 Wk, bk, Wv, bv, pos, cq,
                                                 blk, cs);
    k_cross<<<BATCH * KQ, 256, 0, stream>>>(blk, cs, rres, gamma, beta, out);
}

// Round 7
// 420.700 us; speedup vs baseline: 1.5559x; 1.5559x over previous
//
#include <hip/hip_runtime.h>
#include <hip/hip_bf16.h>

// Problem constants
#define BATCH 32
#define NSEQ  16384
#define DDIM  65
#define CHUNK 64
#define KQ    64
#define NBLK  256          // NSEQ / CHUNK
#define SCALE 0.12403473458920847f   // 65^-0.5

typedef __bf16 bf16x8 __attribute__((ext_vector_type(8)));
typedef float  f32x4  __attribute__((ext_vector_type(4)));
#define MFMA16(a, b, c) __builtin_amdgcn_mfma_f32_16x16x32_bf16(a, b, c, 0, 0, 0)

__device__ __forceinline__ float gelu_exact(float v) {
    return 0.5f * v * (1.0f + erff(v * 0.7071067811865476f));
}

// tanh-approx GELU: |err| <= ~2e-4, far below bf16 rounding of keys/vals.
// (round-0 form, verified at 378 us)
__device__ __forceinline__ float gelu_tanh(float x) {
    float x2 = x * x;
    float t  = 0.7978845608028654f * x * fmaf(0.044715f, x2, 1.0f);
    float e  = __expf(2.0f * t);
    float th = 1.0f - 2.0f * __builtin_amdgcn_rcpf(e + 1.0f);
    return 0.5f * x * (1.0f + th);
}

// ---------------------------------------------------------------------------
// Kernel 1: per-slice partial sums over N (no atomics).  grid (64, 32).
// (round-0 version, proven)
// ---------------------------------------------------------------------------
__global__ __launch_bounds__(256) void k_gavg(const float* __restrict__ x,
                                              float* __restrict__ partial) {
    const int s = blockIdx.x;
    const int b = blockIdx.y;
    const int tid = threadIdx.x;
    const int w = tid >> 6, lane = tid & 63;
    const float* xb = x + (size_t)b * NSEQ * DDIM;
    const int n0 = s * 256;
    float acc = 0.f, acce = 0.f;
    #pragma unroll 4
    for (int i = 0; i < 64; ++i) {
        const float* row = xb + (size_t)(n0 + w + i * 4) * DDIM;
        acc  += row[lane];
        acce += row[64];
    }
    __shared__ float part[4][DDIM];
    part[w][lane] = acc;
    if (lane == 0) part[w][64] = acce;
    __syncthreads();
    if (tid < DDIM) {
        partial[((size_t)b * 64 + s) * DDIM + tid] =
            part[0][tid] + part[1][tid] + part[2][tid] + part[3][tid];
    }
}

// ---------------------------------------------------------------------------
// Kernel 2 (fused mid): grid 32 (one block per b).
//  part A: this block's 320-element slice of the WkT/WvT transpose tables
//          (WT[d][e] = W[e][d], rows 65..79 zero; bf16 [80][64]).
//  part B: reduce partials -> gavg; h = gelu(gavg@Wq1+bq1) kept in LDS;
//          r = gavg@Wr+br -> global.
//  part C: q = (h@Wq2+bq2)*SCALE -> qbf [64][64] bf16 + q64 col
//          (17 outputs per thread, h from LDS).
// Replaces k_prep + k_qgen1 + k_qgen2 (6 launches -> 4); bodies unchanged.
// ---------------------------------------------------------------------------
__global__ __launch_bounds__(256) void k_mid(
    const float* __restrict__ partial,
    const float* __restrict__ Wk,  const float* __restrict__ Wv,
    const float* __restrict__ Wq1, const float* __restrict__ bq1,
    const float* __restrict__ Wr,  const float* __restrict__ br,
    const float* __restrict__ Wq2, const float* __restrict__ bq2,
    __bf16* __restrict__ WkT, __bf16* __restrict__ WvT,
    __bf16* __restrict__ qbf, float* __restrict__ q64,
    float* __restrict__ r_out) {
    const int b = blockIdx.x, tid = threadIdx.x;

    // ---- part A: prep slice (i in [b*320, b*320+320)) ----
    #pragma unroll
    for (int ii = 0; ii < 2; ++ii) {
        const int j2 = ii * 256 + tid;
        if (j2 < 320) {
            const int i = b * 320 + j2;              // 0 .. 10239
            const int m = i / 5120;
            const int j = i - m * 5120;
            const int d = j >> 6, e = j & 63;
            const float* W = m ? Wv : Wk;
            __bf16* T = m ? WvT : WkT;
            T[(size_t)d * 64 + e] =
                (d < DDIM) ? (__bf16)W[e * DDIM + d] : (__bf16)0.0f;
        }
    }

    // ---- part B: gavg reduce, h (LDS), r ----
    __shared__ float g[DDIM];
    __shared__ float hs[DDIM];
    if (tid < DDIM) {
        float a = 0.f;
        const float* p = partial + (size_t)b * 64 * DDIM + tid;
        #pragma unroll 8
        for (int s = 0; s < 64; ++s) a += p[s * DDIM];
        g[tid] = a * (1.0f / 16384.0f);
    }
    __syncthreads();
    if (tid < DDIM) {
        float a = bq1[tid];
        for (int e = 0; e < DDIM; ++e) a += g[e] * Wq1[e * DDIM + tid];
        hs[tid] = gelu_exact(a);
    } else if (tid >= 128 && tid < 128 + DDIM) {
        const int d = tid - 128;
        float a = br[d];
        for (int e = 0; e < DDIM; ++e) a += g[e] * Wr[e * DDIM + d];
        r_out[b * DDIM + d] = a;
    }
    __syncthreads();

    // ---- part C: qgen2 (17 outputs per thread) ----
    #pragma unroll
    for (int it = 0; it < 17; ++it) {
        const int o = it * 256 + tid;
        if (o < KQ * DDIM) {
            float a = bq2[o];
            #pragma unroll 13
            for (int e = 0; e < DDIM; ++e) a += hs[e] * Wq2[e * (KQ * DDIM) + o];
            a *= SCALE;
            const int k = o / DDIM, d = o - k * DDIM;
            if (d < 64) qbf[(size_t)b * 4096 + k * 64 + d] = (__bf16)a;
            else        q64[b * 64 + k] = a;
        }
    }
}

// ---------------------------------------------------------------------------
// Kernel 3 (MFMA): per (b, chunk).  EXACT round-0 body (proven 145 us,
// 48 VGPR, no spill): in-register softmax; LDS 27.9 KB -> 5 blocks/CU.
// D=65: MFMA over 64 + fp32 rank-1 fixup; d=64 output column from fp32 P.
// ---------------------------------------------------------------------------
__global__ __launch_bounds__(256, 5) void k_attn(const float* __restrict__ x,
    const __bf16* __restrict__ qbf, const float* __restrict__ q64,
    const __bf16* __restrict__ WkT, const __bf16* __restrict__ WvT,
    const float* __restrict__ Wk, const float* __restrict__ bkb,
    const float* __restrict__ Wv, const float* __restrict__ bvb,
    const float* __restrict__ pos, const float* __restrict__ cq,
    __bf16* __restrict__ blk_out, float* __restrict__ cs_out) {
    const int nb = blockIdx.x;
    const int b  = blockIdx.y;
    const int tid = threadIdx.x;
    const int lane = tid & 63, w = tid >> 6;
    const int l16 = lane & 15, quad = lane >> 4;

    __shared__ __align__(16) __bf16 xsP[64 * 72];    // x chunk, then P
    __shared__ __align__(16) __bf16 keys[64 * 72];   // [c][d], cols 0..64
    __shared__ __align__(16) __bf16 valsT[64 * 72];  // [d][c], d<64
    __shared__ float vals64[64];                     // vals[c][64] fp32
    __shared__ float xs64[64];                       // x[c][64]

    // ---- phase 1: stage x chunk (div-free, 4 threads per row) ----
    {
        const int c = tid >> 2, g = tid & 3;
        const float* xrow = x + ((size_t)b * NSEQ + (size_t)nb * CHUNK + c) * DDIM;
        __bf16* dst = xsP + c * 72;
        #pragma unroll
        for (int j = 0; j < 16; ++j)
            dst[g + 4 * j] = (__bf16)xrow[g + 4 * j];
        if (g == 0) xs64[c] = xrow[64];
    }
    __syncthreads();

    // ---- phase 2: keys/vals via MFMA (M=c, N=d 5 tiles, K=64) ----
    {
        const __bf16* arow = xsP + (w * 16 + l16) * 72 + quad * 8;
        bf16x8 a0 = *(const bf16x8*)arow;
        bf16x8 a1 = *(const bf16x8*)(arow + 32);
        f32x4 ak[5], av[5];
        const f32x4 z = {0.f, 0.f, 0.f, 0.f};
        #pragma unroll
        for (int nt = 0; nt < 5; ++nt) {
            const __bf16* bkr = WkT + (nt * 16 + l16) * 64 + quad * 8;
            const __bf16* bvr = WvT + (nt * 16 + l16) * 64 + quad * 8;
            ak[nt] = MFMA16(a0, *(const bf16x8*)bkr, z);
            ak[nt] = MFMA16(a1, *(const bf16x8*)(bkr + 32), ak[nt]);
            av[nt] = MFMA16(a0, *(const bf16x8*)bvr, z);
            av[nt] = MFMA16(a1, *(const bf16x8*)(bvr + 32), av[nt]);
        }
        float xe[4];
        #pragma unroll
        for (int r = 0; r < 4; ++r) xe[r] = xs64[w * 16 + quad * 4 + r];
        #pragma unroll
        for (int nt = 0; nt < 5; ++nt) {
            const int d = nt * 16 + l16;
            if (d <= 64) {
                const float wk64d = Wk[64 * DDIM + d];
                const float wv64d = Wv[64 * DDIM + d];
                const float bkd = bkb[d], bvd = bvb[d];
                #pragma unroll
                for (int r = 0; r < 4; ++r) {
                    const int c = w * 16 + quad * 4 + r;
                    const float pv = pos[c * DDIM + d];
                    const float kvv = gelu_tanh(ak[nt][r] + xe[r] * wk64d + bkd) + pv;
                    const float vvv = gelu_tanh(av[nt][r] + xe[r] * wv64d + bvd) + pv;
                    keys[c * 72 + d] = (__bf16)kvv;
                    if (d < 64) valsT[d * 72 + c] = (__bf16)vvv;
                    else        vals64[c] = vvv;
                }
            }
        }
    }
    __syncthreads();

    // ---- phase 3: S = q@keys^T + fixup, in-register softmax, P store,
    //      d=64 output column + its cs contribution ----
    float csr[4];
    {
        const __bf16* aq = qbf + (size_t)b * 4096 + (w * 16 + l16) * 64 + quad * 8;
        bf16x8 qa0 = *(const bf16x8*)aq;
        bf16x8 qa1 = *(const bf16x8*)(aq + 32);
        const f32x4 z = {0.f, 0.f, 0.f, 0.f};
        float st[4][4];                 // [nt][r]
        #pragma unroll
        for (int nt = 0; nt < 4; ++nt) {
            const __bf16* kb = keys + (nt * 16 + l16) * 72 + quad * 8;
            f32x4 sacc = MFMA16(qa0, *(const bf16x8*)kb, z);
            sacc = MFMA16(qa1, *(const bf16x8*)(kb + 32), sacc);
            const float k64c = (float)keys[(nt * 16 + l16) * 72 + 64];
            #pragma unroll
            for (int r = 0; r < 4; ++r)
                st[nt][r] = fmaf(q64[b * 64 + w * 16 + quad * 4 + r], k64c,
                                 sacc[r]) * SCALE;
        }
        // rowwise max over c (4 regs + 16-lane group)
        float mr[4], sum[4], inv[4];
        #pragma unroll
        for (int r = 0; r < 4; ++r) {
            float m = fmaxf(fmaxf(st[0][r], st[1][r]), fmaxf(st[2][r], st[3][r]));
            m = fmaxf(m, __shfl_xor(m, 1));
            m = fmaxf(m, __shfl_xor(m, 2));
            m = fmaxf(m, __shfl_xor(m, 4));
            m = fmaxf(m, __shfl_xor(m, 8));
            mr[r] = m;
            sum[r] = 0.f;
        }
        #pragma unroll
        for (int nt = 0; nt < 4; ++nt)
            #pragma unroll
            for (int r = 0; r < 4; ++r) {
                st[nt][r] = __expf(st[nt][r] - mr[r]);
                sum[r] += st[nt][r];
            }
        #pragma unroll
        for (int r = 0; r < 4; ++r) {
            float s = sum[r];
            s += __shfl_xor(s, 1);
            s += __shfl_xor(s, 2);
            s += __shfl_xor(s, 4);
            s += __shfl_xor(s, 8);
            inv[r] = __builtin_amdgcn_rcpf(s);
        }
        // store P (bf16) into xsP region (xs dead since phase-2 barrier)
        #pragma unroll
        for (int nt = 0; nt < 4; ++nt)
            #pragma unroll
            for (int r = 0; r < 4; ++r)
                xsP[(w * 16 + quad * 4 + r) * 72 + nt * 16 + l16] =
                    (__bf16)(st[nt][r] * inv[r]);
        // d=64 output column from fp32 P
        float v64l[4];
        #pragma unroll
        for (int nt = 0; nt < 4; ++nt) v64l[nt] = vals64[nt * 16 + l16];
        const float cq64 = cq[64];
        #pragma unroll
        for (int r = 0; r < 4; ++r) {
            float o = st[0][r] * v64l[0];
            o = fmaf(st[1][r], v64l[1], o);
            o = fmaf(st[2][r], v64l[2], o);
            o = fmaf(st[3][r], v64l[3], o);
            o += __shfl_xor(o, 1);
            o += __shfl_xor(o, 2);
            o += __shfl_xor(o, 4);
            o += __shfl_xor(o, 8);
            csr[r] = 0.f;
            if (l16 == 0) {
                const float o64 = o * inv[r];
                const int k = w * 16 + quad * 4 + r;
                blk_out[(((size_t)b * KQ + k) * NBLK + nb) * DDIM + 64] =
                    (__bf16)o64;
                csr[r] = o64 * cq64;
            }
        }
    }
    __syncthreads();

    // ---- phase 5: blk = P @ vals (M=k, N=d 4 tiles, K=64) + cs ----
    {
        const __bf16* pr = xsP + (w * 16 + l16) * 72 + quad * 8;
        bf16x8 pa0 = *(const bf16x8*)pr;
        bf16x8 pa1 = *(const bf16x8*)(pr + 32);
        const f32x4 z = {0.f, 0.f, 0.f, 0.f};
        #pragma unroll
        for (int nt = 0; nt < 4; ++nt) {
            const __bf16* vb = valsT + (nt * 16 + l16) * 72 + quad * 8;
            f32x4 o = MFMA16(pa0, *(const bf16x8*)vb, z);
            o = MFMA16(pa1, *(const bf16x8*)(vb + 32), o);
            const int d = nt * 16 + l16;
            const float cqd = cq[d];
            #pragma unroll
            for (int r = 0; r < 4; ++r) {
                const int k = w * 16 + quad * 4 + r;
                blk_out[(((size_t)b * KQ + k) * NBLK + nb) * DDIM + d] =
                    (__bf16)o[r];
                csr[r] = fmaf(o[r], cqd, csr[r]);
            }
        }
        #pragma unroll
        for (int r = 0; r < 4; ++r) {
            float v = csr[r];
            v += __shfl_xor(v, 1);
            v += __shfl_xor(v, 2);
            v += __shfl_xor(v, 4);
            v += __shfl_xor(v, 8);
            if (l16 == 0) {
                const int k = w * 16 + quad * 4 + r;
                cs_out[((size_t)b * KQ + k) * NBLK + nb] = v * SCALE;
            }
        }
    }
}

// ---------------------------------------------------------------------------
// Kernel 4: cross softmax over nb, weighted sum of blk, residual, LayerNorm.
// (round-0 version, proven)
// ---------------------------------------------------------------------------
__global__ __launch_bounds__(256) void k_cross(
    const __bf16* __restrict__ blk, const float* __restrict__ cs,
    const float* __restrict__ r, const float* __restrict__ gamma,
    const float* __restrict__ beta, float* __restrict__ out) {
    const int bk_ = blockIdx.x;
    const int b = bk_ >> 6;
    const int tid = threadIdx.x;
    const int w = tid >> 6, lane = tid & 63;

    __shared__ float ew[NBLK];
    __shared__ float red[4][DDIM];
    __shared__ float vv[DDIM];
    __shared__ float wredA[4];
    __shared__ float stats[2];

    const float v = cs[(size_t)bk_ * NBLK + tid];
    float m = v;
    for (int off = 32; off; off >>= 1) m = fmaxf(m, __shfl_down(m, off));
    if (lane == 0) wredA[w] = m;
    __syncthreads();
    m = fmaxf(fmaxf(wredA[0], wredA[1]), fmaxf(wredA[2], wredA[3]));
    const float e = __expf(v - m);
    ew[tid] = e;
    float s = e;
    for (int off = 32; off; off >>= 1) s += __shfl_down(s, off);
    __syncthreads();
    if (lane == 0) wredA[w] = s;
    __syncthreads();
    const float inv = 1.0f / (wredA[0] + wredA[1] + wredA[2] + wredA[3]);

    const __bf16* base = blk + (size_t)bk_ * NBLK * DDIM;
    float acc = 0.f, acce = 0.f;
    #pragma unroll 4
    for (int i = 0; i < 64; ++i) {
        const int n = w + i * 4;
        const __bf16* row = base + n * DDIM;
        const float wgt = ew[n];
        acc  += wgt * (float)row[lane];
        acce += wgt * (float)row[64];
    }
    red[w][lane] = acc;
    if (lane == 0) red[w][64] = acce;
    __syncthreads();
    if (tid < DDIM) {
        vv[tid] = (red[0][tid] + red[1][tid] + red[2][tid] + red[3][tid]) * inv
                  + r[b * DDIM + tid];
    }
    __syncthreads();
    if (tid < 64) {
        float a  = vv[tid] + (tid == 0 ? vv[64] : 0.f);
        float sq = vv[tid] * vv[tid] + (tid == 0 ? vv[64] * vv[64] : 0.f);
        for (int off = 32; off; off >>= 1) {
            a  += __shfl_down(a, off);
            sq += __shfl_down(sq, off);
        }
        if (tid == 0) {
            const float mu  = a * (1.0f / DDIM);
            const float var = sq * (1.0f / DDIM) - mu * mu;
            stats[0] = mu;
            stats[1] = rsqrtf(var + 1e-5f);
        }
    }
    __syncthreads();
    if (tid < DDIM) {
        out[(size_t)bk_ * DDIM + tid] =
            (vv[tid] - stats[0]) * stats[1] * gamma[tid] + beta[tid];
    }
}

// ---------------------------------------------------------------------------
extern "C" void kernel_launch(void* const* d_in, const int* in_sizes, int n_in,
                              void* d_out, int out_size, void* d_ws, size_t ws_size,
                              hipStream_t stream) {
    const float* x    = (const float*)d_in[0];
    const float* Wq1  = (const float*)d_in[1];
    const float* bq1  = (const float*)d_in[2];
    const float* Wq2  = (const float*)d_in[3];
    const float* bq2  = (const float*)d_in[4];
    const float* Wk   = (const float*)d_in[5];
    const float* bk   = (const float*)d_in[6];
    const float* Wv   = (const float*)d_in[7];
    const float* bv   = (const float*)d_in[8];
    const float* cq   = (const float*)d_in[9];
    const float* pos  = (const float*)d_in[10];
    const float* Wr   = (const float*)d_in[11];
    const float* br   = (const float*)d_in[12];
    const float* gamma= (const float*)d_in[13];
    const float* beta = (const float*)d_in[14];
    float* out = (float*)d_out;

    // workspace layout (byte offsets, all 16B-aligned) -- round-0 layout
    char* w8 = (char*)d_ws;
    float*  partial = (float*)w8;                    // 532480 B @0
    float*  rres    = (float*)(w8 + 532480);         // 8320 B
    float*  q64     = (float*)(w8 + 540800);         // 8192 B
    // 548992..557312 (old hbuf slot) unused
    float*  cs      = (float*)(w8 + 557312);         // 2097152 B
    __bf16* qbf     = (__bf16*)(w8 + 2654464);       // 262144 B
    __bf16* WkT     = (__bf16*)(w8 + 2916608);       // 10240 B
    __bf16* WvT     = (__bf16*)(w8 + 2926848);       // 10240 B
    __bf16* blk     = (__bf16*)(w8 + 2937088);       // 34078720 B [b][k][nb][65]

    k_gavg<<<dim3(64, BATCH), 256, 0, stream>>>(x, partial);
    k_mid<<<BATCH, 256, 0, stream>>>(partial, Wk, Wv, Wq1, bq1, Wr, br,
                                     Wq2, bq2, WkT, WvT, qbf, q64, rres);
    k_attn<<<dim3(NBLK, BATCH), 256, 0, stream>>>(x, qbf, q64, WkT, WvT,
                                                  Wk, bk, Wv, bv, pos, cq,
                                                  blk, cs);
    k_cross<<<BATCH * KQ, 256, 0, stream>>>(blk, cs, rres, gamma, beta, out);
}

// Round 8
// 350.261 us; speedup vs baseline: 1.8688x; 1.2011x over previous
//
#include <hip/hip_runtime.h>
#include <hip/hip_bf16.h>

// Problem constants
#define BATCH 32
#define NSEQ  16384
#define DDIM  65
#define CHUNK 64
#define KQ    64
#define NBLK  256          // NSEQ / CHUNK
#define SCALE 0.12403473458920847f   // 65^-0.5

typedef __bf16 bf16x8 __attribute__((ext_vector_type(8)));
typedef float  f32x4  __attribute__((ext_vector_type(4)));
#define MFMA16(a, b, c) __builtin_amdgcn_mfma_f32_16x16x32_bf16(a, b, c, 0, 0, 0)

__device__ __forceinline__ float gelu_exact(float v) {
    return 0.5f * v * (1.0f + erff(v * 0.7071067811865476f));
}

// tanh-approx GELU in sigmoid form (validated rounds 3-6, same absmax):
// gelu = x * sigmoid(1.5957691x(1+0.044715x^2)); |err| <= ~2e-4.
__device__ __forceinline__ float gelu_s(float x) {
    float x2 = x * x;
    float zz = x * fmaf(-0.07135481627f, x2, -1.59576912161f);  // -2t
    return x * __builtin_amdgcn_rcpf(__expf(zz) + 1.0f);
}

// ---------------------------------------------------------------------------
// Kernel 1: per-slice partial sums over N (round-0 body) + fused prep of the
// K=96-extended weight tables (s==0 blocks only; 32 blocks x 480 elements).
//  WkT bf16 [80][96]: row d<65: [Wk[:,d], Wk[64][d]@e=64? no--] layout:
//    WkT[d][e] = Wk[e][d] for e<65 ; bk[d] at e=65 ; 0 for e>65.   (d<65)
//    WkT[65][e] = Wv[e][64] for e<65 ; bv[64] at e=65 ; 0 else.    (packed)
//    rows 66..79 = 0.
//  WvT bf16 [80][96]: WvT[d][e] = Wv[e][d] e<65 ; bv[d] at e=65 ; 0 else.
// x rows are staged as [x0..x63, x64, 1.0, 0 x30] so one K=96 MFMA chain
// computes W@x + W[64]*x64 + bias with no epilogue fixup.
// ---------------------------------------------------------------------------
__global__ __launch_bounds__(256) void k_gavg(const float* __restrict__ x,
    const float* __restrict__ Wk, const float* __restrict__ Wv,
    const float* __restrict__ bk, const float* __restrict__ bv,
    __bf16* __restrict__ WkT, __bf16* __restrict__ WvT,
    float* __restrict__ partial) {
    const int s = blockIdx.x;
    const int b = blockIdx.y;
    const int tid = threadIdx.x;

    if (s == 0) {   // fused prep: this b-block's 480-element slice
        #pragma unroll
        for (int it = 0; it < 2; ++it) {
            const int j2 = it * 256 + tid;
            if (j2 < 480) {
                const int i = b * 480 + j2;          // 0 .. 15359
                const int m = i / 7680;
                const int j = i - m * 7680;
                const int d = j / 96, e = j - d * 96;
                float v = 0.f;
                if (m == 0) {
                    if (d < DDIM)
                        v = (e < DDIM) ? Wk[e * DDIM + d]
                                       : (e == DDIM ? bk[d] : 0.f);
                    else if (d == DDIM)
                        v = (e < DDIM) ? Wv[e * DDIM + 64]
                                       : (e == DDIM ? bv[64] : 0.f);
                    WkT[(size_t)d * 96 + e] = (__bf16)v;
                } else {
                    if (d < DDIM)
                        v = (e < DDIM) ? Wv[e * DDIM + d]
                                       : (e == DDIM ? bv[d] : 0.f);
                    WvT[(size_t)d * 96 + e] = (__bf16)v;
                }
            }
        }
    }

    const int w = tid >> 6, lane = tid & 63;
    const float* xb = x + (size_t)b * NSEQ * DDIM;
    const int n0 = s * 256;
    float acc = 0.f, acce = 0.f;
    #pragma unroll 4
    for (int i = 0; i < 64; ++i) {
        const float* row = xb + (size_t)(n0 + w + i * 4) * DDIM;
        acc  += row[lane];
        acce += row[64];
    }
    __shared__ float part[4][DDIM];
    part[w][lane] = acc;
    if (lane == 0) part[w][64] = acce;
    __syncthreads();
    if (tid < DDIM) {
        partial[((size_t)b * 64 + s) * DDIM + tid] =
            part[0][tid] + part[1][tid] + part[2][tid] + part[3][tid];
    }
}

// ---------------------------------------------------------------------------
// Kernel 2a: reduce partials -> gavg; h = gelu(gavg@Wq1+bq1); r = gavg@Wr+br.
// (round-0 version, proven)
// ---------------------------------------------------------------------------
__global__ __launch_bounds__(256) void k_qgen1(const float* __restrict__ partial,
    const float* __restrict__ Wq1, const float* __restrict__ bq1,
    const float* __restrict__ Wr,  const float* __restrict__ br,
    float* __restrict__ h_out, float* __restrict__ r_out) {
    const int b = blockIdx.x, tid = threadIdx.x;
    __shared__ float g[DDIM];
    if (tid < DDIM) {
        float a = 0.f;
        const float* p = partial + (size_t)b * 64 * DDIM + tid;
        #pragma unroll 8
        for (int s = 0; s < 64; ++s) a += p[s * DDIM];
        g[tid] = a * (1.0f / 16384.0f);
    }
    __syncthreads();
    if (tid < DDIM) {
        float a = bq1[tid];
        for (int e = 0; e < DDIM; ++e) a += g[e] * Wq1[e * DDIM + tid];
        h_out[b * DDIM + tid] = gelu_exact(a);
    } else if (tid >= 128 && tid < 128 + DDIM) {
        const int d = tid - 128;
        float a = br[d];
        for (int e = 0; e < DDIM; ++e) a += g[e] * Wr[e * DDIM + d];
        r_out[b * DDIM + d] = a;
    }
}

// ---------------------------------------------------------------------------
// Kernel 2b: q = (h@Wq2+bq2)*SCALE -> qbf [64][64] bf16 + q64 col.
// (round-0 version, proven; grid (17, 32) preserves parallelism -- the k_mid
// fusion that collapsed this to 32 blocks cost 42 us)
// ---------------------------------------------------------------------------
__global__ __launch_bounds__(256) void k_qgen2(const float* __restrict__ h_in,
    const float* __restrict__ Wq2, const float* __restrict__ bq2,
    __bf16* __restrict__ qbf, float* __restrict__ q64) {
    const int b = blockIdx.y, tid = threadIdx.x;
    const int o = blockIdx.x * 256 + tid;
    __shared__ float h[DDIM];
    if (tid < DDIM) h[tid] = h_in[b * DDIM + tid];
    __syncthreads();
    if (o >= KQ * DDIM) return;
    float a = bq2[o];
    #pragma unroll 13
    for (int e = 0; e < DDIM; ++e) a += h[e] * Wq2[e * (KQ * DDIM) + o];
    a *= SCALE;
    const int k = o / DDIM, d = o - k * DDIM;
    if (d < 64) qbf[(size_t)b * 4096 + k * 64 + d] = (__bf16)a;
    else        q64[b * 64 + k] = a;
}

// ---------------------------------------------------------------------------
// Kernel 3 (MFMA): per (b, chunk).  Round-0 structure (single chunk, 3
// barriers-equivalent, 5 blocks/CU) with the K=96 bias/fixup fold:
//  * x staged 96-wide: [x0..x64, 1.0, zeros]; keys/vals tiles are 3-MFMA
//    chains over K=96 -> NO per-element fixup, NO bias add, NO Wk/bk loads.
//  * WkT row 65 packs Wv[:,64]+bv[64]: keys tile nt=4 yields keys[c][64]
//    (l16==0) AND vals64[c] (l16==1); separate vals nt=4 tile deleted.
//  * sigmoid-form gelu (7 ops vs 12).
// LDS 30976 B -> still 5 blocks/CU.
// ---------------------------------------------------------------------------
__global__ __launch_bounds__(256, 5) void k_attn(const float* __restrict__ x,
    const __bf16* __restrict__ qbf, const float* __restrict__ q64,
    const __bf16* __restrict__ WkT, const __bf16* __restrict__ WvT,
    const float* __restrict__ pos, const float* __restrict__ cq,
    __bf16* __restrict__ blk_out, float* __restrict__ cs_out) {
    const int nb = blockIdx.x;
    const int b  = blockIdx.y;
    const int tid = threadIdx.x;
    const int lane = tid & 63, w = tid >> 6;
    const int l16 = lane & 15, quad = lane >> 4;

    __shared__ __align__(16) __bf16 xsP[64 * 96];    // x chunk (96-wide), then P
    __shared__ __align__(16) __bf16 keys[64 * 72];   // [c][d], cols 0..64
    __shared__ __align__(16) __bf16 valsT[64 * 72];  // [d][c], d<64
    __shared__ float vals64[64];                     // vals[c][64] fp32

    // ---- phase 1: stage x chunk 96-wide (div-free, 4 threads per row) ----
    {
        const int c = tid >> 2, g = tid & 3;
        const float* xrow = x + ((size_t)b * NSEQ + (size_t)nb * CHUNK + c) * DDIM;
        __bf16* dst = xsP + c * 96;
        #pragma unroll
        for (int j = 0; j < 16; ++j)
            dst[g + 4 * j] = (__bf16)xrow[g + 4 * j];
        if (g == 0) {
            dst[64] = (__bf16)xrow[64];
            dst[65] = (__bf16)1.0f;
            #pragma unroll
            for (int t2 = 66; t2 < 72; ++t2) dst[t2] = (__bf16)0.0f;
        } else {
            #pragma unroll
            for (int t2 = 0; t2 < 8; ++t2) dst[64 + g * 8 + t2] = (__bf16)0.0f;
        }
    }
    __syncthreads();

    // ---- phase 2: keys/vals via K=96 MFMA chains + gelu ----
    {
        const __bf16* arow = xsP + (w * 16 + l16) * 96 + quad * 8;
        bf16x8 a0 = *(const bf16x8*)arow;
        bf16x8 a1 = *(const bf16x8*)(arow + 32);
        bf16x8 a2 = *(const bf16x8*)(arow + 64);
        const f32x4 z = {0.f, 0.f, 0.f, 0.f};

        f32x4 ak[5];
        #pragma unroll
        for (int nt = 0; nt < 5; ++nt) {
            const __bf16* bkr = WkT + (nt * 16 + l16) * 96 + quad * 8;
            ak[nt] = MFMA16(a0, *(const bf16x8*)bkr, z);
            ak[nt] = MFMA16(a1, *(const bf16x8*)(bkr + 32), ak[nt]);
            ak[nt] = MFMA16(a2, *(const bf16x8*)(bkr + 64), ak[nt]);
        }
        #pragma unroll
        for (int nt = 0; nt < 4; ++nt) {
            const int d = nt * 16 + l16;
            #pragma unroll
            for (int r = 0; r < 4; ++r) {
                const int c = w * 16 + quad * 4 + r;
                keys[c * 72 + d] = (__bf16)(gelu_s(ak[nt][r]) + pos[c * DDIM + d]);
            }
        }
        // tile 4: d = 64 + l16; l16==0 -> keys col 64, l16==1 -> vals col 64
        if (l16 == 0) {
            #pragma unroll
            for (int r = 0; r < 4; ++r) {
                const int c = w * 16 + quad * 4 + r;
                keys[c * 72 + 64] = (__bf16)(gelu_s(ak[4][r]) + pos[c * DDIM + 64]);
            }
        } else if (l16 == 1) {
            #pragma unroll
            for (int r = 0; r < 4; ++r) {
                const int c = w * 16 + quad * 4 + r;
                vals64[c] = gelu_s(ak[4][r]) + pos[c * DDIM + 64];
            }
        }

        f32x4 av[4];
        #pragma unroll
        for (int nt = 0; nt < 4; ++nt) {
            const __bf16* bvr = WvT + (nt * 16 + l16) * 96 + quad * 8;
            av[nt] = MFMA16(a0, *(const bf16x8*)bvr, z);
            av[nt] = MFMA16(a1, *(const bf16x8*)(bvr + 32), av[nt]);
            av[nt] = MFMA16(a2, *(const bf16x8*)(bvr + 64), av[nt]);
        }
        #pragma unroll
        for (int nt = 0; nt < 4; ++nt) {
            const int d = nt * 16 + l16;
            #pragma unroll
            for (int r = 0; r < 4; ++r) {
                const int c = w * 16 + quad * 4 + r;
                valsT[d * 72 + c] = (__bf16)(gelu_s(av[nt][r]) + pos[c * DDIM + d]);
            }
        }
    }
    __syncthreads();

    // ---- phase 3: S = q@keys^T + fixup, in-register softmax, P store,
    //      d=64 output column + its cs contribution (round-0 body) ----
    float csr[4];
    {
        const __bf16* aq = qbf + (size_t)b * 4096 + (w * 16 + l16) * 64 + quad * 8;
        bf16x8 qa0 = *(const bf16x8*)aq;
        bf16x8 qa1 = *(const bf16x8*)(aq + 32);
        const f32x4 z = {0.f, 0.f, 0.f, 0.f};
        float st[4][4];                 // [nt][r]
        #pragma unroll
        for (int nt = 0; nt < 4; ++nt) {
            const __bf16* kb = keys + (nt * 16 + l16) * 72 + quad * 8;
            f32x4 sacc = MFMA16(qa0, *(const bf16x8*)kb, z);
            sacc = MFMA16(qa1, *(const bf16x8*)(kb + 32), sacc);
            const float k64c = (float)keys[(nt * 16 + l16) * 72 + 64];
            #pragma unroll
            for (int r = 0; r < 4; ++r)
                st[nt][r] = fmaf(q64[b * 64 + w * 16 + quad * 4 + r], k64c,
                                 sacc[r]) * SCALE;
        }
        // rowwise max over c (4 regs + 16-lane group)
        float mr[4], sum[4], inv[4];
        #pragma unroll
        for (int r = 0; r < 4; ++r) {
            float m = fmaxf(fmaxf(st[0][r], st[1][r]), fmaxf(st[2][r], st[3][r]));
            m = fmaxf(m, __shfl_xor(m, 1));
            m = fmaxf(m, __shfl_xor(m, 2));
            m = fmaxf(m, __shfl_xor(m, 4));
            m = fmaxf(m, __shfl_xor(m, 8));
            mr[r] = m;
            sum[r] = 0.f;
        }
        #pragma unroll
        for (int nt = 0; nt < 4; ++nt)
            #pragma unroll
            for (int r = 0; r < 4; ++r) {
                st[nt][r] = __expf(st[nt][r] - mr[r]);
                sum[r] += st[nt][r];
            }
        #pragma unroll
        for (int r = 0; r < 4; ++r) {
            float s = sum[r];
            s += __shfl_xor(s, 1);
            s += __shfl_xor(s, 2);
            s += __shfl_xor(s, 4);
            s += __shfl_xor(s, 8);
            inv[r] = __builtin_amdgcn_rcpf(s);
        }
        // store P (bf16) into xsP region (x dead since phase-2 barrier)
        #pragma unroll
        for (int nt = 0; nt < 4; ++nt)
            #pragma unroll
            for (int r = 0; r < 4; ++r)
                xsP[(w * 16 + quad * 4 + r) * 96 + nt * 16 + l16] =
                    (__bf16)(st[nt][r] * inv[r]);
        // d=64 output column from fp32 P
        float v64l[4];
        #pragma unroll
        for (int nt = 0; nt < 4; ++nt) v64l[nt] = vals64[nt * 16 + l16];
        const float cq64 = cq[64];
        #pragma unroll
        for (int r = 0; r < 4; ++r) {
            float o = st[0][r] * v64l[0];
            o = fmaf(st[1][r], v64l[1], o);
            o = fmaf(st[2][r], v64l[2], o);
            o = fmaf(st[3][r], v64l[3], o);
            o += __shfl_xor(o, 1);
            o += __shfl_xor(o, 2);
            o += __shfl_xor(o, 4);
            o += __shfl_xor(o, 8);
            csr[r] = 0.f;
            if (l16 == 0) {
                const float o64 = o * inv[r];
                const int k = w * 16 + quad * 4 + r;
                blk_out[(((size_t)b * KQ + k) * NBLK + nb) * DDIM + 64] =
                    (__bf16)o64;
                csr[r] = o64 * cq64;
            }
        }
    }
    __syncthreads();

    // ---- phase 5: blk = P @ vals (round-0 body; P at 96-stride) ----
    {
        const __bf16* pr = xsP + (w * 16 + l16) * 96 + quad * 8;
        bf16x8 pa0 = *(const bf16x8*)pr;
        bf16x8 pa1 = *(const bf16x8*)(pr + 32);
        const f32x4 z = {0.f, 0.f, 0.f, 0.f};
        #pragma unroll
        for (int nt = 0; nt < 4; ++nt) {
            const __bf16* vb = valsT + (nt * 16 + l16) * 72 + quad * 8;
            f32x4 o = MFMA16(pa0, *(const bf16x8*)vb, z);
            o = MFMA16(pa1, *(const bf16x8*)(vb + 32), o);
            const int d = nt * 16 + l16;
            const float cqd = cq[d];
            #pragma unroll
            for (int r = 0; r < 4; ++r) {
                const int k = w * 16 + quad * 4 + r;
                blk_out[(((size_t)b * KQ + k) * NBLK + nb) * DDIM + d] =
                    (__bf16)o[r];
                csr[r] = fmaf(o[r], cqd, csr[r]);
            }
        }
        #pragma unroll
        for (int r = 0; r < 4; ++r) {
            float v = csr[r];
            v += __shfl_xor(v, 1);
            v += __shfl_xor(v, 2);
            v += __shfl_xor(v, 4);
            v += __shfl_xor(v, 8);
            if (l16 == 0) {
                const int k = w * 16 + quad * 4 + r;
                cs_out[((size_t)b * KQ + k) * NBLK + nb] = v * SCALE;
            }
        }
    }
}

// ---------------------------------------------------------------------------
// Kernel 4: cross softmax over nb, weighted sum of blk, residual, LayerNorm.
// (round-0 version, proven)
// ---------------------------------------------------------------------------
__global__ __launch_bounds__(256) void k_cross(
    const __bf16* __restrict__ blk, const float* __restrict__ cs,
    const float* __restrict__ r, const float* __restrict__ gamma,
    const float* __restrict__ beta, float* __restrict__ out) {
    const int bk_ = blockIdx.x;
    const int b = bk_ >> 6;
    const int tid = threadIdx.x;
    const int w = tid >> 6, lane = tid & 63;

    __shared__ float ew[NBLK];
    __shared__ float red[4][DDIM];
    __shared__ float vv[DDIM];
    __shared__ float wredA[4];
    __shared__ float stats[2];

    const float v = cs[(size_t)bk_ * NBLK + tid];
    float m = v;
    for (int off = 32; off; off >>= 1) m = fmaxf(m, __shfl_down(m, off));
    if (lane == 0) wredA[w] = m;
    __syncthreads();
    m = fmaxf(fmaxf(wredA[0], wredA[1]), fmaxf(wredA[2], wredA[3]));
    const float e = __expf(v - m);
    ew[tid] = e;
    float s = e;
    for (int off = 32; off; off >>= 1) s += __shfl_down(s, off);
    __syncthreads();
    if (lane == 0) wredA[w] = s;
    __syncthreads();
    const float inv = 1.0f / (wredA[0] + wredA[1] + wredA[2] + wredA[3]);

    const __bf16* base = blk + (size_t)bk_ * NBLK * DDIM;
    float acc = 0.f, acce = 0.f;
    #pragma unroll 4
    for (int i = 0; i < 64; ++i) {
        const int n = w + i * 4;
        const __bf16* row = base + n * DDIM;
        const float wgt = ew[n];
        acc  += wgt * (float)row[lane];
        acce += wgt * (float)row[64];
    }
    red[w][lane] = acc;
    if (lane == 0) red[w][64] = acce;
    __syncthreads();
    if (tid < DDIM) {
        vv[tid] = (red[0][tid] + red[1][tid] + red[2][tid] + red[3][tid]) * inv
                  + r[b * DDIM + tid];
    }
    __syncthreads();
    if (tid < 64) {
        float a  = vv[tid] + (tid == 0 ? vv[64] : 0.f);
        float sq = vv[tid] * vv[tid] + (tid == 0 ? vv[64] * vv[64] : 0.f);
        for (int off = 32; off; off >>= 1) {
            a  += __shfl_down(a, off);
            sq += __shfl_down(sq, off);
        }
        if (tid == 0) {
            const float mu  = a * (1.0f / DDIM);
            const float var = sq * (1.0f / DDIM) - mu * mu;
            stats[0] = mu;
            stats[1] = rsqrtf(var + 1e-5f);
        }
    }
    __syncthreads();
    if (tid < DDIM) {
        out[(size_t)bk_ * DDIM + tid] =
            (vv[tid] - stats[0]) * stats[1] * gamma[tid] + beta[tid];
    }
}

// ---------------------------------------------------------------------------
extern "C" void kernel_launch(void* const* d_in, const int* in_sizes, int n_in,
                              void* d_out, int out_size, void* d_ws, size_t ws_size,
                              hipStream_t stream) {
    const float* x    = (const float*)d_in[0];
    const float* Wq1  = (const float*)d_in[1];
    const float* bq1  = (const float*)d_in[2];
    const float* Wq2  = (const float*)d_in[3];
    const float* bq2  = (const float*)d_in[4];
    const float* Wk   = (const float*)d_in[5];
    const float* bk   = (const float*)d_in[6];
    const float* Wv   = (const float*)d_in[7];
    const float* bv   = (const float*)d_in[8];
    const float* cq   = (const float*)d_in[9];
    const float* pos  = (const float*)d_in[10];
    const float* Wr   = (const float*)d_in[11];
    const float* br   = (const float*)d_in[12];
    const float* gamma= (const float*)d_in[13];
    const float* beta = (const float*)d_in[14];
    float* out = (float*)d_out;

    // workspace layout (byte offsets, all 16B-aligned)
    char* w8 = (char*)d_ws;
    float*  partial = (float*)w8;                    // 532480 B @0
    float*  rres    = (float*)(w8 + 532480);         // 8320 B
    float*  q64     = (float*)(w8 + 540800);         // 8192 B
    float*  hbuf    = (float*)(w8 + 548992);         // 8320 B
    float*  cs      = (float*)(w8 + 557312);         // 2097152 B
    __bf16* qbf     = (__bf16*)(w8 + 2654464);       // 262144 B
    __bf16* WkT     = (__bf16*)(w8 + 2916608);       // 15360 B [80][96]
    __bf16* WvT     = (__bf16*)(w8 + 2931968);       // 15360 B [80][96]
    __bf16* blk     = (__bf16*)(w8 + 2947328);       // 68157440 B [b][k][nb][65]

    k_gavg<<<dim3(64, BATCH), 256, 0, stream>>>(x, Wk, Wv, bk, bv,
                                                WkT, WvT, partial);
    k_qgen1<<<BATCH, 256, 0, stream>>>(partial, Wq1, bq1, Wr, br, hbuf, rres);
    k_qgen2<<<dim3(17, BATCH), 256, 0, stream>>>(hbuf, Wq2, bq2, qbf, q64);
    k_attn<<<dim3(NBLK, BATCH), 256, 0, stream>>>(x, qbf, q64, WkT, WvT,
                                                  pos, cq, blk, cs);
    k_cross<<<BATCH * KQ, 256, 0, stream>>>(blk, cs, rres, gamma, beta, out);
}

// Round 9
// 348.725 us; speedup vs baseline: 1.8770x; 1.0044x over previous
//
#include <hip/hip_runtime.h>
#include <hip/hip_bf16.h>

// Problem constants
#define BATCH 32
#define NSEQ  16384
#define DDIM  65
#define CHUNK 64
#define KQ    64
#define NBLK  256          // NSEQ / CHUNK
#define SCALE 0.12403473458920847f   // 65^-0.5
#define XSTR  104          // xsP row stride (208 B): banks (52*l16)%32 spread 8-way

typedef __bf16 bf16x8 __attribute__((ext_vector_type(8)));
typedef float  f32x4  __attribute__((ext_vector_type(4)));
#define MFMA16(a, b, c) __builtin_amdgcn_mfma_f32_16x16x32_bf16(a, b, c, 0, 0, 0)

__device__ __forceinline__ float gelu_exact(float v) {
    return 0.5f * v * (1.0f + erff(v * 0.7071067811865476f));
}

// tanh-approx GELU in sigmoid form (validated rounds 3-8, same absmax):
// gelu = x * sigmoid(1.5957691x(1+0.044715x^2)); |err| <= ~2e-4.
__device__ __forceinline__ float gelu_s(float x) {
    float x2 = x * x;
    float zz = x * fmaf(-0.07135481627f, x2, -1.59576912161f);  // -2t
    return x * __builtin_amdgcn_rcpf(__expf(zz) + 1.0f);
}

// ---------------------------------------------------------------------------
// Kernel 1: per-slice partial sums over N (round-0 body) + fused prep of the
// K=96-extended weight tables (s==0 blocks only).  Layout (round-8, proven):
//  WkT bf16 [80][96]: d<65: [Wk[:,d] | bk[d]@e=65 | 0]; d=65: [Wv[:,64] |
//  bv[64]@e=65 | 0]; rows 66..79 = 0.   WvT bf16 [80][96] analogous for Wv.
// ---------------------------------------------------------------------------
__global__ __launch_bounds__(256) void k_gavg(const float* __restrict__ x,
    const float* __restrict__ Wk, const float* __restrict__ Wv,
    const float* __restrict__ bk, const float* __restrict__ bv,
    __bf16* __restrict__ WkT, __bf16* __restrict__ WvT,
    float* __restrict__ partial) {
    const int s = blockIdx.x;
    const int b = blockIdx.y;
    const int tid = threadIdx.x;

    if (s == 0) {   // fused prep: this b-block's 480-element slice
        #pragma unroll
        for (int it = 0; it < 2; ++it) {
            const int j2 = it * 256 + tid;
            if (j2 < 480) {
                const int i = b * 480 + j2;          // 0 .. 15359
                const int m = i / 7680;
                const int j = i - m * 7680;
                const int d = j / 96, e = j - d * 96;
                float v = 0.f;
                if (m == 0) {
                    if (d < DDIM)
                        v = (e < DDIM) ? Wk[e * DDIM + d]
                                       : (e == DDIM ? bk[d] : 0.f);
                    else if (d == DDIM)
                        v = (e < DDIM) ? Wv[e * DDIM + 64]
                                       : (e == DDIM ? bv[64] : 0.f);
                    WkT[(size_t)d * 96 + e] = (__bf16)v;
                } else {
                    if (d < DDIM)
                        v = (e < DDIM) ? Wv[e * DDIM + d]
                                       : (e == DDIM ? bv[d] : 0.f);
                    WvT[(size_t)d * 96 + e] = (__bf16)v;
                }
            }
        }
    }

    const int w = tid >> 6, lane = tid & 63;
    const float* xb = x + (size_t)b * NSEQ * DDIM;
    const int n0 = s * 256;
    float acc = 0.f, acce = 0.f;
    #pragma unroll 4
    for (int i = 0; i < 64; ++i) {
        const float* row = xb + (size_t)(n0 + w + i * 4) * DDIM;
        acc  += row[lane];
        acce += row[64];
    }
    __shared__ float part[4][DDIM];
    part[w][lane] = acc;
    if (lane == 0) part[w][64] = acce;
    __syncthreads();
    if (tid < DDIM) {
        partial[((size_t)b * 64 + s) * DDIM + tid] =
            part[0][tid] + part[1][tid] + part[2][tid] + part[3][tid];
    }
}

// ---------------------------------------------------------------------------
// Kernel 2 (fused qgen): grid (17, 32).  Every block redundantly computes
// gavg (reduce of 64 L2-resident partial slices) and h = gelu(gavg@Wq1+bq1)
// -- ~130 cheap parallel iterations -- then its 256-output slice of
// q = (h@Wq2+bq2)*SCALE.  Block x==16 (only 64 q outputs) also computes
// r = gavg@Wr+br.  Replaces k_qgen1 (grid 32: 87.5% of chip idle) + k_qgen2.
// ---------------------------------------------------------------------------
__global__ __launch_bounds__(256) void k_qgen(const float* __restrict__ partial,
    const float* __restrict__ Wq1, const float* __restrict__ bq1,
    const float* __restrict__ Wq2, const float* __restrict__ bq2,
    const float* __restrict__ Wr,  const float* __restrict__ br,
    __bf16* __restrict__ qbf, float* __restrict__ q64,
    float* __restrict__ r_out) {
    const int b = blockIdx.y, tid = threadIdx.x;
    __shared__ float g[DDIM];
    __shared__ float h[DDIM];
    if (tid < DDIM) {
        float a = 0.f;
        const float* p = partial + (size_t)b * 64 * DDIM + tid;
        #pragma unroll 8
        for (int s = 0; s < 64; ++s) a += p[s * DDIM];
        g[tid] = a * (1.0f / 16384.0f);
    }
    __syncthreads();
    if (tid < DDIM) {
        float a = bq1[tid];
        for (int e = 0; e < DDIM; ++e) a += g[e] * Wq1[e * DDIM + tid];
        h[tid] = gelu_exact(a);
    }
    __syncthreads();
    const int o = blockIdx.x * 256 + tid;
    if (o < KQ * DDIM) {
        float a = bq2[o];
        #pragma unroll 13
        for (int e = 0; e < DDIM; ++e) a += h[e] * Wq2[e * (KQ * DDIM) + o];
        a *= SCALE;
        const int k = o / DDIM, d = o - k * DDIM;
        if (d < 64) qbf[(size_t)b * 4096 + k * 64 + d] = (__bf16)a;
        else        q64[b * 64 + k] = a;
    }
    if (blockIdx.x == 16 && tid >= 128 && tid < 128 + DDIM) {
        const int d = tid - 128;
        float a = br[d];
        for (int e = 0; e < DDIM; ++e) a += g[e] * Wr[e * DDIM + d];
        r_out[b * DDIM + d] = a;
    }
}

// ---------------------------------------------------------------------------
// Kernel 3 (MFMA): per (b, chunk).  Round-8 body (proven 119 us) with the
// xsP row stride padded 96 -> 104 elements: ds_read_b128 bank starts
// (52*l16 + 4*quad) mod 32 hit 8 distinct banks x 2 lanes = free 2-way
// (the 96-stride mapped to {0,16} only -> 8-way conflict, 7.7M cycles).
// LDS 32000 B -> still 5 blocks/CU.
// ---------------------------------------------------------------------------
__global__ __launch_bounds__(256, 5) void k_attn(const float* __restrict__ x,
    const __bf16* __restrict__ qbf, const float* __restrict__ q64,
    const __bf16* __restrict__ WkT, const __bf16* __restrict__ WvT,
    const float* __restrict__ pos, const float* __restrict__ cq,
    __bf16* __restrict__ blk_out, float* __restrict__ cs_out) {
    const int nb = blockIdx.x;
    const int b  = blockIdx.y;
    const int tid = threadIdx.x;
    const int lane = tid & 63, w = tid >> 6;
    const int l16 = lane & 15, quad = lane >> 4;

    __shared__ __align__(16) __bf16 xsP[64 * XSTR];  // x chunk (96 cols), then P
    __shared__ __align__(16) __bf16 keys[64 * 72];   // [c][d], cols 0..64
    __shared__ __align__(16) __bf16 valsT[64 * 72];  // [d][c], d<64
    __shared__ float vals64[64];                     // vals[c][64] fp32

    // ---- phase 1: stage x chunk 96-wide (div-free, 4 threads per row) ----
    {
        const int c = tid >> 2, g = tid & 3;
        const float* xrow = x + ((size_t)b * NSEQ + (size_t)nb * CHUNK + c) * DDIM;
        __bf16* dst = xsP + c * XSTR;
        #pragma unroll
        for (int j = 0; j < 16; ++j)
            dst[g + 4 * j] = (__bf16)xrow[g + 4 * j];
        if (g == 0) {
            dst[64] = (__bf16)xrow[64];
            dst[65] = (__bf16)1.0f;
            #pragma unroll
            for (int t2 = 66; t2 < 72; ++t2) dst[t2] = (__bf16)0.0f;
        } else {
            #pragma unroll
            for (int t2 = 0; t2 < 8; ++t2) dst[64 + g * 8 + t2] = (__bf16)0.0f;
        }
    }
    __syncthreads();

    // ---- phase 2: keys/vals via K=96 MFMA chains + gelu ----
    {
        const __bf16* arow = xsP + (w * 16 + l16) * XSTR + quad * 8;
        bf16x8 a0 = *(const bf16x8*)arow;
        bf16x8 a1 = *(const bf16x8*)(arow + 32);
        bf16x8 a2 = *(const bf16x8*)(arow + 64);
        const f32x4 z = {0.f, 0.f, 0.f, 0.f};

        f32x4 ak[5];
        #pragma unroll
        for (int nt = 0; nt < 5; ++nt) {
            const __bf16* bkr = WkT + (nt * 16 + l16) * 96 + quad * 8;
            ak[nt] = MFMA16(a0, *(const bf16x8*)bkr, z);
            ak[nt] = MFMA16(a1, *(const bf16x8*)(bkr + 32), ak[nt]);
            ak[nt] = MFMA16(a2, *(const bf16x8*)(bkr + 64), ak[nt]);
        }
        #pragma unroll
        for (int nt = 0; nt < 4; ++nt) {
            const int d = nt * 16 + l16;
            #pragma unroll
            for (int r = 0; r < 4; ++r) {
                const int c = w * 16 + quad * 4 + r;
                keys[c * 72 + d] = (__bf16)(gelu_s(ak[nt][r]) + pos[c * DDIM + d]);
            }
        }
        // tile 4: d = 64 + l16; l16==0 -> keys col 64, l16==1 -> vals col 64
        if (l16 == 0) {
            #pragma unroll
            for (int r = 0; r < 4; ++r) {
                const int c = w * 16 + quad * 4 + r;
                keys[c * 72 + 64] = (__bf16)(gelu_s(ak[4][r]) + pos[c * DDIM + 64]);
            }
        } else if (l16 == 1) {
            #pragma unroll
            for (int r = 0; r < 4; ++r) {
                const int c = w * 16 + quad * 4 + r;
                vals64[c] = gelu_s(ak[4][r]) + pos[c * DDIM + 64];
            }
        }

        f32x4 av[4];
        #pragma unroll
        for (int nt = 0; nt < 4; ++nt) {
            const __bf16* bvr = WvT + (nt * 16 + l16) * 96 + quad * 8;
            av[nt] = MFMA16(a0, *(const bf16x8*)bvr, z);
            av[nt] = MFMA16(a1, *(const bf16x8*)(bvr + 32), av[nt]);
            av[nt] = MFMA16(a2, *(const bf16x8*)(bvr + 64), av[nt]);
        }
        #pragma unroll
        for (int nt = 0; nt < 4; ++nt) {
            const int d = nt * 16 + l16;
            #pragma unroll
            for (int r = 0; r < 4; ++r) {
                const int c = w * 16 + quad * 4 + r;
                valsT[d * 72 + c] = (__bf16)(gelu_s(av[nt][r]) + pos[c * DDIM + d]);
            }
        }
    }
    __syncthreads();

    // ---- phase 3: S = q@keys^T + fixup, in-register softmax, P store,
    //      d=64 output column + its cs contribution ----
    float csr[4];
    {
        const __bf16* aq = qbf + (size_t)b * 4096 + (w * 16 + l16) * 64 + quad * 8;
        bf16x8 qa0 = *(const bf16x8*)aq;
        bf16x8 qa1 = *(const bf16x8*)(aq + 32);
        const f32x4 z = {0.f, 0.f, 0.f, 0.f};
        float st[4][4];                 // [nt][r]
        #pragma unroll
        for (int nt = 0; nt < 4; ++nt) {
            const __bf16* kb = keys + (nt * 16 + l16) * 72 + quad * 8;
            f32x4 sacc = MFMA16(qa0, *(const bf16x8*)kb, z);
            sacc = MFMA16(qa1, *(const bf16x8*)(kb + 32), sacc);
            const float k64c = (float)keys[(nt * 16 + l16) * 72 + 64];
            #pragma unroll
            for (int r = 0; r < 4; ++r)
                st[nt][r] = fmaf(q64[b * 64 + w * 16 + quad * 4 + r], k64c,
                                 sacc[r]) * SCALE;
        }
        // rowwise max over c (4 regs + 16-lane group)
        float mr[4], sum[4], inv[4];
        #pragma unroll
        for (int r = 0; r < 4; ++r) {
            float m = fmaxf(fmaxf(st[0][r], st[1][r]), fmaxf(st[2][r], st[3][r]));
            m = fmaxf(m, __shfl_xor(m, 1));
            m = fmaxf(m, __shfl_xor(m, 2));
            m = fmaxf(m, __shfl_xor(m, 4));
            m = fmaxf(m, __shfl_xor(m, 8));
            mr[r] = m;
            sum[r] = 0.f;
        }
        #pragma unroll
        for (int nt = 0; nt < 4; ++nt)
            #pragma unroll
            for (int r = 0; r < 4; ++r) {
                st[nt][r] = __expf(st[nt][r] - mr[r]);
                sum[r] += st[nt][r];
            }
        #pragma unroll
        for (int r = 0; r < 4; ++r) {
            float s = sum[r];
            s += __shfl_xor(s, 1);
            s += __shfl_xor(s, 2);
            s += __shfl_xor(s, 4);
            s += __shfl_xor(s, 8);
            inv[r] = __builtin_amdgcn_rcpf(s);
        }
        // store P (bf16) into xsP region (x dead since phase-2 barrier)
        #pragma unroll
        for (int nt = 0; nt < 4; ++nt)
            #pragma unroll
            for (int r = 0; r < 4; ++r)
                xsP[(w * 16 + quad * 4 + r) * XSTR + nt * 16 + l16] =
                    (__bf16)(st[nt][r] * inv[r]);
        // d=64 output column from fp32 P
        float v64l[4];
        #pragma unroll
        for (int nt = 0; nt < 4; ++nt) v64l[nt] = vals64[nt * 16 + l16];
        const float cq64 = cq[64];
        #pragma unroll
        for (int r = 0; r < 4; ++r) {
            float o = st[0][r] * v64l[0];
            o = fmaf(st[1][r], v64l[1], o);
            o = fmaf(st[2][r], v64l[2], o);
            o = fmaf(st[3][r], v64l[3], o);
            o += __shfl_xor(o, 1);
            o += __shfl_xor(o, 2);
            o += __shfl_xor(o, 4);
            o += __shfl_xor(o, 8);
            csr[r] = 0.f;
            if (l16 == 0) {
                const float o64 = o * inv[r];
                const int k = w * 16 + quad * 4 + r;
                blk_out[(((size_t)b * KQ + k) * NBLK + nb) * DDIM + 64] =
                    (__bf16)o64;
                csr[r] = o64 * cq64;
            }
        }
    }
    __syncthreads();

    // ---- phase 5: blk = P @ vals (P at XSTR stride) + cs ----
    {
        const __bf16* pr = xsP + (w * 16 + l16) * XSTR + quad * 8;
        bf16x8 pa0 = *(const bf16x8*)pr;
        bf16x8 pa1 = *(const bf16x8*)(pr + 32);
        const f32x4 z = {0.f, 0.f, 0.f, 0.f};
        #pragma unroll
        for (int nt = 0; nt < 4; ++nt) {
            const __bf16* vb = valsT + (nt * 16 + l16) * 72 + quad * 8;
            f32x4 o = MFMA16(pa0, *(const bf16x8*)vb, z);
            o = MFMA16(pa1, *(const bf16x8*)(vb + 32), o);
            const int d = nt * 16 + l16;
            const float cqd = cq[d];
            #pragma unroll
            for (int r = 0; r < 4; ++r) {
                const int k = w * 16 + quad * 4 + r;
                blk_out[(((size_t)b * KQ + k) * NBLK + nb) * DDIM + d] =
                    (__bf16)o[r];
                csr[r] = fmaf(o[r], cqd, csr[r]);
            }
        }
        #pragma unroll
        for (int r = 0; r < 4; ++r) {
            float v = csr[r];
            v += __shfl_xor(v, 1);
            v += __shfl_xor(v, 2);
            v += __shfl_xor(v, 4);
            v += __shfl_xor(v, 8);
            if (l16 == 0) {
                const int k = w * 16 + quad * 4 + r;
                cs_out[((size_t)b * KQ + k) * NBLK + nb] = v * SCALE;
            }
        }
    }
}

// ---------------------------------------------------------------------------
// Kernel 4: cross softmax over nb, weighted sum of blk, residual, LayerNorm.
// (round-0 version, proven)
// ---------------------------------------------------------------------------
__global__ __launch_bounds__(256) void k_cross(
    const __bf16* __restrict__ blk, const float* __restrict__ cs,
    const float* __restrict__ r, const float* __restrict__ gamma,
    const float* __restrict__ beta, float* __restrict__ out) {
    const int bk_ = blockIdx.x;
    const int b = bk_ >> 6;
    const int tid = threadIdx.x;
    const int w = tid >> 6, lane = tid & 63;

    __shared__ float ew[NBLK];
    __shared__ float red[4][DDIM];
    __shared__ float vv[DDIM];
    __shared__ float wredA[4];
    __shared__ float stats[2];

    const float v = cs[(size_t)bk_ * NBLK + tid];
    float m = v;
    for (int off = 32; off; off >>= 1) m = fmaxf(m, __shfl_down(m, off));
    if (lane == 0) wredA[w] = m;
    __syncthreads();
    m = fmaxf(fmaxf(wredA[0], wredA[1]), fmaxf(wredA[2], wredA[3]));
    const float e = __expf(v - m);
    ew[tid] = e;
    float s = e;
    for (int off = 32; off; off >>= 1) s += __shfl_down(s, off);
    __syncthreads();
    if (lane == 0) wredA[w] = s;
    __syncthreads();
    const float inv = 1.0f / (wredA[0] + wredA[1] + wredA[2] + wredA[3]);

    const __bf16* base = blk + (size_t)bk_ * NBLK * DDIM;
    float acc = 0.f, acce = 0.f;
    #pragma unroll 4
    for (int i = 0; i < 64; ++i) {
        const int n = w + i * 4;
        const __bf16* row = base + n * DDIM;
        const float wgt = ew[n];
        acc  += wgt * (float)row[lane];
        acce += wgt * (float)row[64];
    }
    red[w][lane] = acc;
    if (lane == 0) red[w][64] = acce;
    __syncthreads();
    if (tid < DDIM) {
        vv[tid] = (red[0][tid] + red[1][tid] + red[2][tid] + red[3][tid]) * inv
                  + r[b * DDIM + tid];
    }
    __syncthreads();
    if (tid < 64) {
        float a  = vv[tid] + (tid == 0 ? vv[64] : 0.f);
        float sq = vv[tid] * vv[tid] + (tid == 0 ? vv[64] * vv[64] : 0.f);
        for (int off = 32; off; off >>= 1) {
            a  += __shfl_down(a, off);
            sq += __shfl_down(sq, off);
        }
        if (tid == 0) {
            const float mu  = a * (1.0f / DDIM);
            const float var = sq * (1.0f / DDIM) - mu * mu;
            stats[0] = mu;
            stats[1] = rsqrtf(var + 1e-5f);
        }
    }
    __syncthreads();
    if (tid < DDIM) {
        out[(size_t)bk_ * DDIM + tid] =
            (vv[tid] - stats[0]) * stats[1] * gamma[tid] + beta[tid];
    }
}

// ---------------------------------------------------------------------------
extern "C" void kernel_launch(void* const* d_in, const int* in_sizes, int n_in,
                              void* d_out, int out_size, void* d_ws, size_t ws_size,
                              hipStream_t stream) {
    const float* x    = (const float*)d_in[0];
    const float* Wq1  = (const float*)d_in[1];
    const float* bq1  = (const float*)d_in[2];
    const float* Wq2  = (const float*)d_in[3];
    const float* bq2  = (const float*)d_in[4];
    const float* Wk   = (const float*)d_in[5];
    const float* bk   = (const float*)d_in[6];
    const float* Wv   = (const float*)d_in[7];
    const float* bv   = (const float*)d_in[8];
    const float* cq   = (const float*)d_in[9];
    const float* pos  = (const float*)d_in[10];
    const float* Wr   = (const float*)d_in[11];
    const float* br   = (const float*)d_in[12];
    const float* gamma= (const float*)d_in[13];
    const float* beta = (const float*)d_in[14];
    float* out = (float*)d_out;

    // workspace layout (byte offsets, all 16B-aligned)
    char* w8 = (char*)d_ws;
    float*  partial = (float*)w8;                    // 532480 B @0
    float*  rres    = (float*)(w8 + 532480);         // 8320 B
    float*  q64     = (float*)(w8 + 540800);         // 8192 B
    // 548992..557312 (old hbuf slot) unused
    float*  cs      = (float*)(w8 + 557312);         // 2097152 B
    __bf16* qbf     = (__bf16*)(w8 + 2654464);       // 262144 B
    __bf16* WkT     = (__bf16*)(w8 + 2916608);       // 15360 B [80][96]
    __bf16* WvT     = (__bf16*)(w8 + 2931968);       // 15360 B [80][96]
    __bf16* blk     = (__bf16*)(w8 + 2947328);       // 68157440 B [b][k][nb][65]

    k_gavg<<<dim3(64, BATCH), 256, 0, stream>>>(x, Wk, Wv, bk, bv,
                                                WkT, WvT, partial);
    k_qgen<<<dim3(17, BATCH), 256, 0, stream>>>(partial, Wq1, bq1, Wq2, bq2,
                                                Wr, br, qbf, q64, rres);
    k_attn<<<dim3(NBLK, BATCH), 256, 0, stream>>>(x, qbf, q64, WkT, WvT,
                                                  pos, cq, blk, cs);
    k_cross<<<BATCH * KQ, 256, 0, stream>>>(blk, cs, rres, gamma, beta, out);
}